// Round 10
// baseline (155.945 us; speedup 1.0000x reference)
//
#include <hip/hip_runtime.h>

#define BB 16
#define NN 512
#define NI 32
#define NHEAD 8
#define NH 512
#define NO 64
#define ROWS (BB*NN)   // 8192
#define EPSV 1e-5f
#define SLOPE 0.05f

typedef __attribute__((ext_vector_type(4))) float f32x4;
typedef __attribute__((ext_vector_type(8))) short s16x8;

static __device__ __forceinline__ ushort f2bf(float f) {
    union { float f; unsigned u; } v; v.f = f;
    unsigned r = v.u + 0x7fff + ((v.u >> 16) & 1);   // RNE
    return (ushort)(r >> 16);
}

static __device__ __forceinline__ unsigned cvt_pk_bf16(float lo, float hi) {
    unsigned r;
    asm("v_cvt_pk_bf16_f32 %0, %1, %2" : "=v"(r) : "v"(lo), "v"(hi));
    return r;
}

static __device__ __forceinline__ float bf2f(ushort u) {
    union { unsigned u; float f; } v; v.u = ((unsigned)u) << 16;
    return v.f;
}

#define GLOAD_LDS16(g, l) __builtin_amdgcn_global_load_lds( \
    (const __attribute__((address_space(1))) void*)(g),     \
    (__attribute__((address_space(3))) void*)(l), 16, 0, 0)

// getv x^T tile swizzle (ushort index space).
#define XTI(i, m) ((((i) * 512) + (m)) ^ (((i) & 7) << 3))

#define NL2 (-1.4426950408889634f)   // -log2(e)
#define PL2 (2.8853901617779268f)    //  2*log2(e)

// ---------------------------------------------------------------------------
// Dispatch 1: blocks [0,512) = getv, 2 tiles per block; blocks [512,576) =
// wconv + stats zero. D-exponent in expanded form (R9-verified):
//   arg = base + pmt[m] + sx*px + sy*py + sz*pz
// ---------------------------------------------------------------------------
__global__ __launch_bounds__(256, 2) void k_getv_wconv(
    const float* __restrict__ x, const float* __restrict__ Qm,
    ushort* __restrict__ Vb,
    const float* __restrict__ W1, const float* __restrict__ W2,
    const float* __restrict__ W3,
    ushort* __restrict__ W1b, ushort* __restrict__ W2b, ushort* __restrict__ W3b,
    float* __restrict__ st) {
    const int blk = blockIdx.x;
    const int t = threadIdx.x;

    if (blk >= 512) {   // wconv + stats-zero
        const int gid = (blk - 512) * 256 + t;   // 0..16383
        if (gid < 2176) st[gid] = 0.f;
#pragma unroll
        for (int r = 0; r < 2; ++r) {
            int i = gid + r * 16384;
            if (i < 32768) {
                float4 v = reinterpret_cast<const float4*>(W1)[i];
                *reinterpret_cast<ushort4*>(W1b + (size_t)i * 4) =
                    make_ushort4(f2bf(v.x), f2bf(v.y), f2bf(v.z), f2bf(v.w));
            }
        }
#pragma unroll
        for (int r = 0; r < 4; ++r) {
            int i = gid + r * 16384;
            float4 v = reinterpret_cast<const float4*>(W2)[i];
            *reinterpret_cast<ushort4*>(W2b + (size_t)i * 4) =
                make_ushort4(f2bf(v.x), f2bf(v.y), f2bf(v.z), f2bf(v.w));
        }
        if (gid < 8192) {
            float4 v = reinterpret_cast<const float4*>(W3)[gid];
            *reinterpret_cast<ushort4*>(W3b + (size_t)gid * 4) =
                make_ushort4(f2bf(v.x), f2bf(v.y), f2bf(v.z), f2bf(v.w));
        }
        return;
    }

    __shared__ ushort xT[32 * 512];   // 32 KB, swizzled [i][m]
    __shared__ float poss[NN * 4];    // 8 KB: (px,py,pz,pmt)
    const int b = blk >> 5;
    const int tpair = blk & 31;
    const int lane = t & 63;
    const int w = t >> 6;

    const float4* xg = reinterpret_cast<const float4*>(x + (size_t)b * NN * NI);
    const int i4 = t & 7;
#pragma unroll
    for (int j = 0; j < 4; ++j) {
        int m0 = ((t >> 3) + j * 32) * 4;          // 0..508, step 4
        float4 a0 = xg[(m0 + 0) * 8 + i4];
        float4 a1 = xg[(m0 + 1) * 8 + i4];
        float4 a2 = xg[(m0 + 2) * 8 + i4];
        float4 a3 = xg[(m0 + 3) * 8 + i4];
        uint2 p;
        p = make_uint2(cvt_pk_bf16(a0.x, a1.x), cvt_pk_bf16(a2.x, a3.x));
        *reinterpret_cast<uint2*>(&xT[XTI(i4 * 4 + 0, m0)]) = p;
        p = make_uint2(cvt_pk_bf16(a0.y, a1.y), cvt_pk_bf16(a2.y, a3.y));
        *reinterpret_cast<uint2*>(&xT[XTI(i4 * 4 + 1, m0)]) = p;
        p = make_uint2(cvt_pk_bf16(a0.z, a1.z), cvt_pk_bf16(a2.z, a3.z));
        *reinterpret_cast<uint2*>(&xT[XTI(i4 * 4 + 2, m0)]) = p;
        p = make_uint2(cvt_pk_bf16(a0.w, a1.w), cvt_pk_bf16(a2.w, a3.w));
        *reinterpret_cast<uint2*>(&xT[XTI(i4 * 4 + 3, m0)]) = p;
        if (i4 == 0) {
            *reinterpret_cast<float4*>(&poss[(m0 + 0) * 4]) = make_float4(
                a0.x, a0.y, a0.z, NL2 * fmaf(a0.x, a0.x, fmaf(a0.y, a0.y, a0.z * a0.z)));
            *reinterpret_cast<float4*>(&poss[(m0 + 1) * 4]) = make_float4(
                a1.x, a1.y, a1.z, NL2 * fmaf(a1.x, a1.x, fmaf(a1.y, a1.y, a1.z * a1.z)));
            *reinterpret_cast<float4*>(&poss[(m0 + 2) * 4]) = make_float4(
                a2.x, a2.y, a2.z, NL2 * fmaf(a2.x, a2.x, fmaf(a2.y, a2.y, a2.z * a2.z)));
            *reinterpret_cast<float4*>(&poss[(m0 + 3) * 4]) = make_float4(
                a3.x, a3.y, a3.z, NL2 * fmaf(a3.x, a3.x, fmaf(a3.y, a3.y, a3.z * a3.z)));
        }
    }
    __syncthreads();

    const int la = lane & 15;
    const int mko = (lane >> 4) * 8;
#pragma unroll 1
    for (int rep = 0; rep < 2; ++rep) {
        const int tile = tpair * 2 + rep;          // 0..63
        const int h = tile >> 3;
        const int nb = (tile & 7) * 64;
        const float qx = Qm[h * 3 + 0], qy = Qm[h * 3 + 1], qz = Qm[h * 3 + 2];
        const int n_a = nb + w * 16 + la;
        float4 pa = *reinterpret_cast<const float4*>(&poss[n_a * 4]);
        const float c0 = pa.x - qx, c1 = pa.y - qy, c2 = pa.z - qz;
        const float sx = PL2 * c0, sy = PL2 * c1, sz = PL2 * c2;
        const float base = NL2 * fmaf(c0, c0, fmaf(c1, c1, c2 * c2));

        f32x4 acc0 = {0.f, 0.f, 0.f, 0.f}, acc1 = {0.f, 0.f, 0.f, 0.f};
        for (int mc = 0; mc < NN; mc += 32) {
            float d[8];
#pragma unroll
            for (int j = 0; j < 8; ++j) {
                float4 pm = *reinterpret_cast<const float4*>(&poss[(mc + mko + j) * 4]);
                float arg = fmaf(sx, pm.x, fmaf(sy, pm.y, fmaf(sz, pm.z, base + pm.w)));
                d[j] = exp2f(arg);
            }
            union { s16x8 v; unsigned u[4]; } af;
#pragma unroll
            for (int j = 0; j < 4; ++j) af.u[j] = cvt_pk_bf16(d[2 * j], d[2 * j + 1]);
            s16x8 bb0 = *reinterpret_cast<const s16x8*>(&xT[XTI(la, mc + mko)]);
            s16x8 bb1 = *reinterpret_cast<const s16x8*>(&xT[XTI(la + 16, mc + mko)]);
            acc0 = __builtin_amdgcn_mfma_f32_16x16x32_bf16(af.v, bb0, acc0, 0, 0, 0);
            acc1 = __builtin_amdgcn_mfma_f32_16x16x32_bf16(af.v, bb1, acc1, 0, 0, 0);
        }
        const int i = la;
#pragma unroll
        for (int r = 0; r < 4; ++r) {
            int n = nb + w * 16 + (lane >> 4) * 4 + r;
            float v0 = acc0[r], v1 = acc1[r];
            if (i < 3) {
                const float* p = &poss[n * 4];
                v0 -= (i == 0) ? p[0] : (i == 1) ? p[1] : p[2];
            }
            ushort* vp = Vb + (((size_t)(b * NN + n)) * NHEAD + h) * NI;
            vp[i] = f2bf(v0);
            vp[i + 16] = f2bf(v1);
        }
    }
}

// ---------------------------------------------------------------------------
// Dispatch 2: gemm1. A bf16 (V), gload_lds staging, BM=128, fused stats.
// C written as bf16 RAW (pre-BN).
// ---------------------------------------------------------------------------
__global__ __launch_bounds__(256) void k_gemm1(const ushort* __restrict__ A,
                                               const ushort* __restrict__ W,
                                               const float* __restrict__ bias,
                                               ushort* __restrict__ Cb,
                                               float* __restrict__ sums,
                                               float* __restrict__ sumsq) {
    constexpr int K = 256, NC = 512, KS = K / 32;
    __shared__ ushort As[2][4096];
    __shared__ ushort Bs[2][2048];
    __shared__ float red[2][64];
    const int t = threadIdx.x;
    const int lane = t & 63;
    const int w = t >> 6;
    const int m0 = blockIdx.y * 128;
    const int n0 = blockIdx.x * 64;
    const int la = lane & 15;
    const int lk = (lane >> 4) * 8;
    const int lks = lk ^ ((la & 3) << 3);
    const int srow = t >> 2;
    const int scol = ((t & 3) ^ (srow & 3)) * 8;

    if (t < 64) { red[0][t] = 0.f; red[1][t] = 0.f; }

    f32x4 acc[2][4];
#pragma unroll
    for (int fm = 0; fm < 2; ++fm)
#pragma unroll
        for (int fn = 0; fn < 4; ++fn) acc[fm][fn] = (f32x4){0.f, 0.f, 0.f, 0.f};

    auto STAGE = [&](int buf, int k0) {
        GLOAD_LDS16(A + (size_t)(m0 + srow) * K + k0 + scol, &As[buf][t * 8]);
        GLOAD_LDS16(A + (size_t)(m0 + 64 + srow) * K + k0 + scol, &As[buf][2048 + t * 8]);
        GLOAD_LDS16(W + (size_t)(n0 + srow) * K + k0 + scol, &Bs[buf][t * 8]);
    };

    STAGE(0, 0);
    __syncthreads();
    int cur = 0;
    for (int ks = 0; ks < KS; ++ks) {
        if (ks + 1 < KS) STAGE(cur ^ 1, (ks + 1) * 32);
        s16x8 b0 = *reinterpret_cast<const s16x8*>(&Bs[cur][(0 + la) * 32 + lks]);
        s16x8 b1 = *reinterpret_cast<const s16x8*>(&Bs[cur][(16 + la) * 32 + lks]);
        s16x8 b2 = *reinterpret_cast<const s16x8*>(&Bs[cur][(32 + la) * 32 + lks]);
        s16x8 b3 = *reinterpret_cast<const s16x8*>(&Bs[cur][(48 + la) * 32 + lks]);
#pragma unroll
        for (int fm = 0; fm < 2; ++fm) {
            s16x8 a = *reinterpret_cast<const s16x8*>(&As[cur][(w * 32 + fm * 16 + la) * 32 + lks]);
            acc[fm][0] = __builtin_amdgcn_mfma_f32_16x16x32_bf16(a, b0, acc[fm][0], 0, 0, 0);
            acc[fm][1] = __builtin_amdgcn_mfma_f32_16x16x32_bf16(a, b1, acc[fm][1], 0, 0, 0);
            acc[fm][2] = __builtin_amdgcn_mfma_f32_16x16x32_bf16(a, b2, acc[fm][2], 0, 0, 0);
            acc[fm][3] = __builtin_amdgcn_mfma_f32_16x16x32_bf16(a, b3, acc[fm][3], 0, 0, 0);
        }
        __syncthreads();
        cur ^= 1;
    }

    float bv[4], s[4] = {}, q[4] = {};
#pragma unroll
    for (int fn = 0; fn < 4; ++fn) bv[fn] = bias[n0 + fn * 16 + la];
#pragma unroll
    for (int fm = 0; fm < 2; ++fm)
#pragma unroll
        for (int fn = 0; fn < 4; ++fn)
#pragma unroll
            for (int r = 0; r < 4; ++r) {
                int row = m0 + w * 32 + fm * 16 + (lane >> 4) * 4 + r;
                float v = acc[fm][fn][r] + bv[fn];
                Cb[(size_t)row * NC + n0 + fn * 16 + la] = f2bf(v);
                s[fn] += v; q[fn] += v * v;
            }
#pragma unroll
    for (int fn = 0; fn < 4; ++fn) {
        s[fn] += __shfl_xor(s[fn], 16); s[fn] += __shfl_xor(s[fn], 32);
        q[fn] += __shfl_xor(q[fn], 16); q[fn] += __shfl_xor(q[fn], 32);
    }
    if (lane < 16) {
#pragma unroll
        for (int fn = 0; fn < 4; ++fn) {
            atomicAdd(&red[0][fn * 16 + lane], s[fn]);
            atomicAdd(&red[1][fn * 16 + lane], q[fn]);
        }
    }
    __syncthreads();
    if (t < 64) {
        atomicAdd(&sums[n0 + t], red[0][t]);
        atomicAdd(&sumsq[n0 + t], red[1][t]);
    }
}

// ---------------------------------------------------------------------------
// Dispatch 3: gemm2, retiled BM=64 x BN=128 (halves fused-BN VALU redundancy
// 8x -> 4x). A = bf16 RAW Y1; BN1+leaky in-register post-ds_read.
// Wave w owns rows [w*16, w*16+16) x all 128 cols (8 n-frags).
// ---------------------------------------------------------------------------
template <int K, int NC>
__global__ __launch_bounds__(256) void k_gemm_bn(const ushort* __restrict__ Araw,
                                                 const ushort* __restrict__ W,
                                                 const float* __restrict__ bias,
                                                 const float* __restrict__ psum,
                                                 const float* __restrict__ psumsq,
                                                 const float* __restrict__ pg,
                                                 const float* __restrict__ pbt,
                                                 ushort* __restrict__ Cb,
                                                 float* __restrict__ sums,
                                                 float* __restrict__ sumsq) {
    constexpr int KS = K / 32;
    __shared__ ushort As[2][2048];    // 64 x 32
    __shared__ ushort Bs[2][4096];    // 128 x 32
    __shared__ float ca[K], cd[K];
    __shared__ float red[2][128];
    const int t = threadIdx.x;
    const int lane = t & 63;
    const int w = t >> 6;
    const int m0 = blockIdx.y * 64;
    const int n0 = blockIdx.x * 128;
    const int la = lane & 15;
    const int lk = (lane >> 4) * 8;
    const int lks = lk ^ ((la & 3) << 3);
    const int srow = t >> 2;                        // 0..63
    const int scol = ((t & 3) ^ (srow & 3)) * 8;
    const float invn = 1.f / (float)ROWS;

    for (int c = t; c < K; c += 256) {
        float m = psum[c] * invn;
        float var = psumsq[c] * invn - m * m;
        float a = pg[c] * rsqrtf(var + EPSV);
        ca[c] = a;
        cd[c] = pbt[c] - m * a;
    }
    if (t < 128) { red[0][t] = 0.f; red[1][t] = 0.f; }

    // B staging: 128x32 via 2 gloads; rowB=(t>>2)+l*64, colB=((t&3)^((t>>2)&3))*8
    auto STAGE = [&](int buf, int k0) {
        GLOAD_LDS16(Araw + (size_t)(m0 + srow) * K + k0 + scol, &As[buf][t * 8]);
        GLOAD_LDS16(W + (size_t)(n0 + srow) * K + k0 + scol, &Bs[buf][t * 8]);
        GLOAD_LDS16(W + (size_t)(n0 + 64 + srow) * K + k0 + scol, &Bs[buf][2048 + t * 8]);
    };

    f32x4 acc[8];
#pragma unroll
    for (int fn = 0; fn < 8; ++fn) acc[fn] = (f32x4){0.f, 0.f, 0.f, 0.f};

    STAGE(0, 0);
    __syncthreads();           // covers ca/cd + red + staged data
    int cur = 0;
    for (int ks = 0; ks < KS; ++ks) {
        const int k0 = ks * 32;
        if (ks + 1 < KS) STAGE(cur ^ 1, (ks + 1) * 32);
        // BN coefs for this k-slice
        float4 ka0 = *reinterpret_cast<const float4*>(&ca[k0 + lk]);
        float4 ka1 = *reinterpret_cast<const float4*>(&ca[k0 + lk + 4]);
        float4 kd0 = *reinterpret_cast<const float4*>(&cd[k0 + lk]);
        float4 kd1 = *reinterpret_cast<const float4*>(&cd[k0 + lk + 4]);
        float kaf[8] = {ka0.x, ka0.y, ka0.z, ka0.w, ka1.x, ka1.y, ka1.z, ka1.w};
        float kdf[8] = {kd0.x, kd0.y, kd0.z, kd0.w, kd1.x, kd1.y, kd1.z, kd1.w};
        union { s16x8 v; ushort us[8]; } araw;
        araw.v = *reinterpret_cast<const s16x8*>(&As[cur][(w * 16 + la) * 32 + lks]);
        float y[8];
#pragma unroll
        for (int e = 0; e < 8; ++e) {
            float f = bf2f(araw.us[e]);
            float z = fmaf(kaf[e], f, kdf[e]);
            y[e] = fmaxf(z, 0.f) + SLOPE * fminf(z, 0.f);
        }
        union { s16x8 v; unsigned u[4]; } af;
#pragma unroll
        for (int p = 0; p < 4; ++p) af.u[p] = cvt_pk_bf16(y[2 * p], y[2 * p + 1]);
#pragma unroll
        for (int fn = 0; fn < 8; ++fn) {
            s16x8 bb = *reinterpret_cast<const s16x8*>(&Bs[cur][(fn * 16 + la) * 32 + lks]);
            acc[fn] = __builtin_amdgcn_mfma_f32_16x16x32_bf16(af.v, bb, acc[fn], 0, 0, 0);
        }
        __syncthreads();
        cur ^= 1;
    }

    float bv[8], s[8] = {}, q[8] = {};
#pragma unroll
    for (int fn = 0; fn < 8; ++fn) bv[fn] = bias[n0 + fn * 16 + la];
#pragma unroll
    for (int fn = 0; fn < 8; ++fn)
#pragma unroll
        for (int r = 0; r < 4; ++r) {
            int row = m0 + w * 16 + (lane >> 4) * 4 + r;
            float v = acc[fn][r] + bv[fn];
            Cb[(size_t)row * NC + n0 + fn * 16 + la] = f2bf(v);
            s[fn] += v; q[fn] += v * v;
        }
#pragma unroll
    for (int fn = 0; fn < 8; ++fn) {
        s[fn] += __shfl_xor(s[fn], 16); s[fn] += __shfl_xor(s[fn], 32);
        q[fn] += __shfl_xor(q[fn], 16); q[fn] += __shfl_xor(q[fn], 32);
    }
    if (lane < 16) {
#pragma unroll
        for (int fn = 0; fn < 8; ++fn) {
            atomicAdd(&red[0][fn * 16 + lane], s[fn]);
            atomicAdd(&red[1][fn * 16 + lane], q[fn]);
        }
    }
    __syncthreads();
    if (t < 128) {
        atomicAdd(&sums[n0 + t], red[0][t]);
        atomicAdd(&sumsq[n0 + t], red[1][t]);
    }
}

// ---------------------------------------------------------------------------
// Dispatch 4: gemm3. A = bf16 RAW Y2 (16x32 tile staged by wave 0),
// BN2+leaky in-register post-ds_read; C fp32 + stats.
// ---------------------------------------------------------------------------
__global__ __launch_bounds__(256) void k_gemm3_bn(const ushort* __restrict__ Araw,
                                                  const ushort* __restrict__ W,
                                                  const float* __restrict__ bias,
                                                  const float* __restrict__ psum,
                                                  const float* __restrict__ psumsq,
                                                  const float* __restrict__ pg,
                                                  const float* __restrict__ pbt,
                                                  float* __restrict__ C,
                                                  float* __restrict__ sums,
                                                  float* __restrict__ sumsq) {
    constexpr int K = 512, KS = 16;
    __shared__ ushort As[2][512];
    __shared__ ushort Bs[2][2048];
    __shared__ float ca[K], cd[K];
    const int t = threadIdx.x;
    const int lane = t & 63;
    const int w = t >> 6;
    const int m0 = blockIdx.x * 16;
    const int la = lane & 15;
    const int lk = (lane >> 4) * 8;
    const int lks = lk ^ ((la & 3) << 3);
    const int srow = t >> 2;
    const int scol = ((t & 3) ^ (srow & 3)) * 8;
    const int srow3 = lane >> 2;
    const int scol3 = ((lane & 3) ^ (srow3 & 3)) * 8;
    const float invn = 1.f / (float)ROWS;

    for (int c = t; c < K; c += 256) {
        float m = psum[c] * invn;
        float var = psumsq[c] * invn - m * m;
        float a = pg[c] * rsqrtf(var + EPSV);
        ca[c] = a;
        cd[c] = pbt[c] - m * a;
    }

    auto STAGE = [&](int buf, int k0) {
        if (w == 0)
            GLOAD_LDS16(Araw + (size_t)(m0 + srow3) * K + k0 + scol3, &As[buf][lane * 8]);
        GLOAD_LDS16(W + (size_t)srow * K + k0 + scol, &Bs[buf][t * 8]);
    };

    f32x4 acc = {0.f, 0.f, 0.f, 0.f};
    STAGE(0, 0);
    __syncthreads();
    int cur = 0;
    for (int ks = 0; ks < KS; ++ks) {
        const int k0 = ks * 32;
        if (ks + 1 < KS) STAGE(cur ^ 1, (ks + 1) * 32);
        float4 ka0 = *reinterpret_cast<const float4*>(&ca[k0 + lk]);
        float4 ka1 = *reinterpret_cast<const float4*>(&ca[k0 + lk + 4]);
        float4 kd0 = *reinterpret_cast<const float4*>(&cd[k0 + lk]);
        float4 kd1 = *reinterpret_cast<const float4*>(&cd[k0 + lk + 4]);
        float kaf[8] = {ka0.x, ka0.y, ka0.z, ka0.w, ka1.x, ka1.y, ka1.z, ka1.w};
        float kdf[8] = {kd0.x, kd0.y, kd0.z, kd0.w, kd1.x, kd1.y, kd1.z, kd1.w};
        union { s16x8 v; ushort us[8]; } araw;
        araw.v = *reinterpret_cast<const s16x8*>(&As[cur][la * 32 + lks]);
        float y[8];
#pragma unroll
        for (int e = 0; e < 8; ++e) {
            float f = bf2f(araw.us[e]);
            float z = fmaf(kaf[e], f, kdf[e]);
            y[e] = fmaxf(z, 0.f) + SLOPE * fminf(z, 0.f);
        }
        union { s16x8 v; unsigned u[4]; } af;
#pragma unroll
        for (int p = 0; p < 4; ++p) af.u[p] = cvt_pk_bf16(y[2 * p], y[2 * p + 1]);
        s16x8 bb = *reinterpret_cast<const s16x8*>(&Bs[cur][(w * 16 + la) * 32 + lks]);
        acc = __builtin_amdgcn_mfma_f32_16x16x32_bf16(af.v, bb, acc, 0, 0, 0);
        __syncthreads();
        cur ^= 1;
    }

    float bv = bias[w * 16 + la];
    float s = 0.f, q = 0.f;
#pragma unroll
    for (int r = 0; r < 4; ++r) {
        int row = m0 + (lane >> 4) * 4 + r;
        float v = acc[r] + bv;
        C[(size_t)row * NO + w * 16 + la] = v;
        s += v; q += v * v;
    }
    s += __shfl_xor(s, 16); s += __shfl_xor(s, 32);
    q += __shfl_xor(q, 16); q += __shfl_xor(q, 32);
    if (lane < 16) {
        atomicAdd(&sums[w * 16 + la], s);
        atomicAdd(&sumsq[w * 16 + la], q);
    }
}

// ---------------------------------------------------------------------------
// Dispatch 5: final BN -> out.
// ---------------------------------------------------------------------------
__global__ __launch_bounds__(256) void k_bn3(const float* __restrict__ Yin,
                                             float* __restrict__ Yout,
                                             const float* __restrict__ sums,
                                             const float* __restrict__ sumsq,
                                             const float* __restrict__ g,
                                             const float* __restrict__ bt) {
    const float invn = 1.f / (float)ROWS;
    int e = blockIdx.x * 256 + threadIdx.x;
    int c0 = (e * 4) & (NO - 1);
    float4 v = reinterpret_cast<const float4*>(Yin)[e];
    float vv[4] = {v.x, v.y, v.z, v.w};
    float oo[4];
#pragma unroll
    for (int j = 0; j < 4; ++j) {
        int c = c0 + j;
        float m = sums[c] * invn;
        float var = sumsq[c] * invn - m * m;
        float rs = rsqrtf(var + EPSV);
        oo[j] = (vv[j] - m) * rs * g[c] + bt[c];
    }
    reinterpret_cast<float4*>(Yout)[e] = make_float4(oo[0], oo[1], oo[2], oo[3]);
}

extern "C" void kernel_launch(void* const* d_in, const int* in_sizes, int n_in,
                              void* d_out, int out_size, void* d_ws, size_t ws_size,
                              hipStream_t stream) {
    const float* x   = (const float*)d_in[0];
    const float* Q   = (const float*)d_in[1];
    const float* W1  = (const float*)d_in[2];
    const float* b1  = (const float*)d_in[3];
    const float* g1  = (const float*)d_in[4];
    const float* bt1 = (const float*)d_in[5];
    const float* W2  = (const float*)d_in[6];
    const float* b2  = (const float*)d_in[7];
    const float* g2  = (const float*)d_in[8];
    const float* bt2 = (const float*)d_in[9];
    const float* W3  = (const float*)d_in[10];
    const float* b3  = (const float*)d_in[11];
    const float* g3  = (const float*)d_in[12];
    const float* bt3 = (const float*)d_in[13];
    float* out = (float*)d_out;

    char* wsb = (char*)d_ws;
    ushort* Vb   = (ushort*)wsb;                     // [0,4M)   bf16 8192x256
    ushort* Y1rb = (ushort*)(wsb + (4u << 20));      // [4,12M)  bf16 raw 8192x512
    ushort* Y2rb = (ushort*)(wsb + (12u << 20));     // [12,20M) bf16 raw 8192x512
    float*  Yr3  = (float*)(wsb + (20u << 20));      // [20,22M) fp32 8192x64
    ushort* W1b  = (ushort*)(wsb + (24u << 20));
    ushort* W2b  = W1b + 512 * 256;
    ushort* W3b  = W2b + 512 * 512;
    float*  st   = (float*)(W3b + 64 * 512);
    float* s1 = st;        float* q1 = s1 + 512;
    float* s2 = q1 + 512;  float* q2 = s2 + 512;
    float* s3 = q2 + 512;  float* q3 = s3 + 64;

    k_getv_wconv<<<576, 256, 0, stream>>>(x, Q, Vb, W1, W2, W3, W1b, W2b, W3b, st);

    k_gemm1<<<dim3(8, 64), 256, 0, stream>>>(Vb, W1b, b1, Y1rb, s1, q1);

    k_gemm_bn<512, 512><<<dim3(4, 128), 256, 0, stream>>>(
        Y1rb, W2b, b2, s1, q1, g1, bt1, Y2rb, s2, q2);

    k_gemm3_bn<<<512, 256, 0, stream>>>(
        Y2rb, W3b, b3, s2, q2, g2, bt2, Yr3, s3, q3);

    k_bn3<<<512, 256, 0, stream>>>(Yr3, out, s3, q3, g3, bt3);
}

// Round 11
// 153.785 us; speedup vs baseline: 1.0140x; 1.0140x over previous
//
#include <hip/hip_runtime.h>

#define BB 16
#define NN 512
#define NI 32
#define NHEAD 8
#define NH 512
#define NO 64
#define ROWS (BB*NN)   // 8192
#define EPSV 1e-5f
#define SLOPE 0.05f

typedef __attribute__((ext_vector_type(4))) float f32x4;
typedef __attribute__((ext_vector_type(8))) short s16x8;

static __device__ __forceinline__ ushort f2bf(float f) {
    union { float f; unsigned u; } v; v.f = f;
    unsigned r = v.u + 0x7fff + ((v.u >> 16) & 1);   // RNE
    return (ushort)(r >> 16);
}

static __device__ __forceinline__ unsigned cvt_pk_bf16(float lo, float hi) {
    unsigned r;
    asm("v_cvt_pk_bf16_f32 %0, %1, %2" : "=v"(r) : "v"(lo), "v"(hi));
    return r;
}

static __device__ __forceinline__ float bf2f(ushort u) {
    union { unsigned u; float f; } v; v.u = ((unsigned)u) << 16;
    return v.f;
}

#define GLOAD_LDS16(g, l) __builtin_amdgcn_global_load_lds( \
    (const __attribute__((address_space(1))) void*)(g),     \
    (__attribute__((address_space(3))) void*)(l), 16, 0, 0)

// getv x^T tile swizzle (ushort index space).
#define XTI(i, m) ((((i) * 512) + (m)) ^ (((i) & 7) << 3))

#define NL2 (-1.4426950408889634f)   // -log2(e)
#define PL2 (2.8853901617779268f)    //  2*log2(e)

// ---------------------------------------------------------------------------
// Dispatch 1: blocks [0,512) = getv, 2 tiles per block; blocks [512,576) =
// wconv + stats zero. D-exponent in expanded form (R9-verified):
//   arg = base + pmt[m] + sx*px + sy*py + sz*pz
// ---------------------------------------------------------------------------
__global__ __launch_bounds__(256, 2) void k_getv_wconv(
    const float* __restrict__ x, const float* __restrict__ Qm,
    ushort* __restrict__ Vb,
    const float* __restrict__ W1, const float* __restrict__ W2,
    const float* __restrict__ W3,
    ushort* __restrict__ W1b, ushort* __restrict__ W2b, ushort* __restrict__ W3b,
    float* __restrict__ st) {
    const int blk = blockIdx.x;
    const int t = threadIdx.x;

    if (blk >= 512) {   // wconv + stats-zero
        const int gid = (blk - 512) * 256 + t;   // 0..16383
        if (gid < 2176) st[gid] = 0.f;
#pragma unroll
        for (int r = 0; r < 2; ++r) {
            int i = gid + r * 16384;
            if (i < 32768) {
                float4 v = reinterpret_cast<const float4*>(W1)[i];
                *reinterpret_cast<ushort4*>(W1b + (size_t)i * 4) =
                    make_ushort4(f2bf(v.x), f2bf(v.y), f2bf(v.z), f2bf(v.w));
            }
        }
#pragma unroll
        for (int r = 0; r < 4; ++r) {
            int i = gid + r * 16384;
            float4 v = reinterpret_cast<const float4*>(W2)[i];
            *reinterpret_cast<ushort4*>(W2b + (size_t)i * 4) =
                make_ushort4(f2bf(v.x), f2bf(v.y), f2bf(v.z), f2bf(v.w));
        }
        if (gid < 8192) {
            float4 v = reinterpret_cast<const float4*>(W3)[gid];
            *reinterpret_cast<ushort4*>(W3b + (size_t)gid * 4) =
                make_ushort4(f2bf(v.x), f2bf(v.y), f2bf(v.z), f2bf(v.w));
        }
        return;
    }

    __shared__ ushort xT[32 * 512];   // 32 KB, swizzled [i][m]
    __shared__ float poss[NN * 4];    // 8 KB: (px,py,pz,pmt)
    const int b = blk >> 5;
    const int tpair = blk & 31;
    const int lane = t & 63;
    const int w = t >> 6;

    const float4* xg = reinterpret_cast<const float4*>(x + (size_t)b * NN * NI);
    const int i4 = t & 7;
#pragma unroll
    for (int j = 0; j < 4; ++j) {
        int m0 = ((t >> 3) + j * 32) * 4;          // 0..508, step 4
        float4 a0 = xg[(m0 + 0) * 8 + i4];
        float4 a1 = xg[(m0 + 1) * 8 + i4];
        float4 a2 = xg[(m0 + 2) * 8 + i4];
        float4 a3 = xg[(m0 + 3) * 8 + i4];
        uint2 p;
        p = make_uint2(cvt_pk_bf16(a0.x, a1.x), cvt_pk_bf16(a2.x, a3.x));
        *reinterpret_cast<uint2*>(&xT[XTI(i4 * 4 + 0, m0)]) = p;
        p = make_uint2(cvt_pk_bf16(a0.y, a1.y), cvt_pk_bf16(a2.y, a3.y));
        *reinterpret_cast<uint2*>(&xT[XTI(i4 * 4 + 1, m0)]) = p;
        p = make_uint2(cvt_pk_bf16(a0.z, a1.z), cvt_pk_bf16(a2.z, a3.z));
        *reinterpret_cast<uint2*>(&xT[XTI(i4 * 4 + 2, m0)]) = p;
        p = make_uint2(cvt_pk_bf16(a0.w, a1.w), cvt_pk_bf16(a2.w, a3.w));
        *reinterpret_cast<uint2*>(&xT[XTI(i4 * 4 + 3, m0)]) = p;
        if (i4 == 0) {
            *reinterpret_cast<float4*>(&poss[(m0 + 0) * 4]) = make_float4(
                a0.x, a0.y, a0.z, NL2 * fmaf(a0.x, a0.x, fmaf(a0.y, a0.y, a0.z * a0.z)));
            *reinterpret_cast<float4*>(&poss[(m0 + 1) * 4]) = make_float4(
                a1.x, a1.y, a1.z, NL2 * fmaf(a1.x, a1.x, fmaf(a1.y, a1.y, a1.z * a1.z)));
            *reinterpret_cast<float4*>(&poss[(m0 + 2) * 4]) = make_float4(
                a2.x, a2.y, a2.z, NL2 * fmaf(a2.x, a2.x, fmaf(a2.y, a2.y, a2.z * a2.z)));
            *reinterpret_cast<float4*>(&poss[(m0 + 3) * 4]) = make_float4(
                a3.x, a3.y, a3.z, NL2 * fmaf(a3.x, a3.x, fmaf(a3.y, a3.y, a3.z * a3.z)));
        }
    }
    __syncthreads();

    const int la = lane & 15;
    const int mko = (lane >> 4) * 8;
#pragma unroll 1
    for (int rep = 0; rep < 2; ++rep) {
        const int tile = tpair * 2 + rep;          // 0..63
        const int h = tile >> 3;
        const int nb = (tile & 7) * 64;
        const float qx = Qm[h * 3 + 0], qy = Qm[h * 3 + 1], qz = Qm[h * 3 + 2];
        const int n_a = nb + w * 16 + la;
        float4 pa = *reinterpret_cast<const float4*>(&poss[n_a * 4]);
        const float c0 = pa.x - qx, c1 = pa.y - qy, c2 = pa.z - qz;
        const float sx = PL2 * c0, sy = PL2 * c1, sz = PL2 * c2;
        const float base = NL2 * fmaf(c0, c0, fmaf(c1, c1, c2 * c2));

        f32x4 acc0 = {0.f, 0.f, 0.f, 0.f}, acc1 = {0.f, 0.f, 0.f, 0.f};
        for (int mc = 0; mc < NN; mc += 32) {
            float d[8];
#pragma unroll
            for (int j = 0; j < 8; ++j) {
                float4 pm = *reinterpret_cast<const float4*>(&poss[(mc + mko + j) * 4]);
                float arg = fmaf(sx, pm.x, fmaf(sy, pm.y, fmaf(sz, pm.z, base + pm.w)));
                d[j] = exp2f(arg);
            }
            union { s16x8 v; unsigned u[4]; } af;
#pragma unroll
            for (int j = 0; j < 4; ++j) af.u[j] = cvt_pk_bf16(d[2 * j], d[2 * j + 1]);
            s16x8 bb0 = *reinterpret_cast<const s16x8*>(&xT[XTI(la, mc + mko)]);
            s16x8 bb1 = *reinterpret_cast<const s16x8*>(&xT[XTI(la + 16, mc + mko)]);
            acc0 = __builtin_amdgcn_mfma_f32_16x16x32_bf16(af.v, bb0, acc0, 0, 0, 0);
            acc1 = __builtin_amdgcn_mfma_f32_16x16x32_bf16(af.v, bb1, acc1, 0, 0, 0);
        }
        const int i = la;
#pragma unroll
        for (int r = 0; r < 4; ++r) {
            int n = nb + w * 16 + (lane >> 4) * 4 + r;
            float v0 = acc0[r], v1 = acc1[r];
            if (i < 3) {
                const float* p = &poss[n * 4];
                v0 -= (i == 0) ? p[0] : (i == 1) ? p[1] : p[2];
            }
            ushort* vp = Vb + (((size_t)(b * NN + n)) * NHEAD + h) * NI;
            vp[i] = f2bf(v0);
            vp[i + 16] = f2bf(v1);
        }
    }
}

// ---------------------------------------------------------------------------
// Dispatch 2: gemm1. A bf16 (V), gload_lds staging, BM=128, fused stats.
// C written as bf16 RAW (pre-BN).
// ---------------------------------------------------------------------------
__global__ __launch_bounds__(256) void k_gemm1(const ushort* __restrict__ A,
                                               const ushort* __restrict__ W,
                                               const float* __restrict__ bias,
                                               ushort* __restrict__ Cb,
                                               float* __restrict__ sums,
                                               float* __restrict__ sumsq) {
    constexpr int K = 256, NC = 512, KS = K / 32;
    __shared__ ushort As[2][4096];
    __shared__ ushort Bs[2][2048];
    __shared__ float red[2][64];
    const int t = threadIdx.x;
    const int lane = t & 63;
    const int w = t >> 6;
    const int m0 = blockIdx.y * 128;
    const int n0 = blockIdx.x * 64;
    const int la = lane & 15;
    const int lk = (lane >> 4) * 8;
    const int lks = lk ^ ((la & 3) << 3);
    const int srow = t >> 2;
    const int scol = ((t & 3) ^ (srow & 3)) * 8;

    if (t < 64) { red[0][t] = 0.f; red[1][t] = 0.f; }

    f32x4 acc[2][4];
#pragma unroll
    for (int fm = 0; fm < 2; ++fm)
#pragma unroll
        for (int fn = 0; fn < 4; ++fn) acc[fm][fn] = (f32x4){0.f, 0.f, 0.f, 0.f};

    auto STAGE = [&](int buf, int k0) {
        GLOAD_LDS16(A + (size_t)(m0 + srow) * K + k0 + scol, &As[buf][t * 8]);
        GLOAD_LDS16(A + (size_t)(m0 + 64 + srow) * K + k0 + scol, &As[buf][2048 + t * 8]);
        GLOAD_LDS16(W + (size_t)(n0 + srow) * K + k0 + scol, &Bs[buf][t * 8]);
    };

    STAGE(0, 0);
    __syncthreads();
    int cur = 0;
    for (int ks = 0; ks < KS; ++ks) {
        if (ks + 1 < KS) STAGE(cur ^ 1, (ks + 1) * 32);
        s16x8 b0 = *reinterpret_cast<const s16x8*>(&Bs[cur][(0 + la) * 32 + lks]);
        s16x8 b1 = *reinterpret_cast<const s16x8*>(&Bs[cur][(16 + la) * 32 + lks]);
        s16x8 b2 = *reinterpret_cast<const s16x8*>(&Bs[cur][(32 + la) * 32 + lks]);
        s16x8 b3 = *reinterpret_cast<const s16x8*>(&Bs[cur][(48 + la) * 32 + lks]);
#pragma unroll
        for (int fm = 0; fm < 2; ++fm) {
            s16x8 a = *reinterpret_cast<const s16x8*>(&As[cur][(w * 32 + fm * 16 + la) * 32 + lks]);
            acc[fm][0] = __builtin_amdgcn_mfma_f32_16x16x32_bf16(a, b0, acc[fm][0], 0, 0, 0);
            acc[fm][1] = __builtin_amdgcn_mfma_f32_16x16x32_bf16(a, b1, acc[fm][1], 0, 0, 0);
            acc[fm][2] = __builtin_amdgcn_mfma_f32_16x16x32_bf16(a, b2, acc[fm][2], 0, 0, 0);
            acc[fm][3] = __builtin_amdgcn_mfma_f32_16x16x32_bf16(a, b3, acc[fm][3], 0, 0, 0);
        }
        __syncthreads();
        cur ^= 1;
    }

    float bv[4], s[4] = {}, q[4] = {};
#pragma unroll
    for (int fn = 0; fn < 4; ++fn) bv[fn] = bias[n0 + fn * 16 + la];
#pragma unroll
    for (int fm = 0; fm < 2; ++fm)
#pragma unroll
        for (int fn = 0; fn < 4; ++fn)
#pragma unroll
            for (int r = 0; r < 4; ++r) {
                int row = m0 + w * 32 + fm * 16 + (lane >> 4) * 4 + r;
                float v = acc[fm][fn][r] + bv[fn];
                Cb[(size_t)row * NC + n0 + fn * 16 + la] = f2bf(v);
                s[fn] += v; q[fn] += v * v;
            }
#pragma unroll
    for (int fn = 0; fn < 4; ++fn) {
        s[fn] += __shfl_xor(s[fn], 16); s[fn] += __shfl_xor(s[fn], 32);
        q[fn] += __shfl_xor(q[fn], 16); q[fn] += __shfl_xor(q[fn], 32);
    }
    if (lane < 16) {
#pragma unroll
        for (int fn = 0; fn < 4; ++fn) {
            atomicAdd(&red[0][fn * 16 + lane], s[fn]);
            atomicAdd(&red[1][fn * 16 + lane], q[fn]);
        }
    }
    __syncthreads();
    if (t < 64) {
        atomicAdd(&sums[n0 + t], red[0][t]);
        atomicAdd(&sumsq[n0 + t], red[1][t]);
    }
}

// ---------------------------------------------------------------------------
// Dispatch 3: gemm2 (R9-verified tile BM=128 x BN=64). A = bf16 RAW Y1
// (gload_lds staged); BN1+leaky applied IN-REGISTER after ds_read, before
// MFMA. C written as bf16 RAW + fused stats.
// ---------------------------------------------------------------------------
template <int K, int NC>
__global__ __launch_bounds__(256) void k_gemm_bn(const ushort* __restrict__ Araw,
                                                 const ushort* __restrict__ W,
                                                 const float* __restrict__ bias,
                                                 const float* __restrict__ psum,
                                                 const float* __restrict__ psumsq,
                                                 const float* __restrict__ pg,
                                                 const float* __restrict__ pbt,
                                                 ushort* __restrict__ Cb,
                                                 float* __restrict__ sums,
                                                 float* __restrict__ sumsq) {
    constexpr int KS = K / 32;
    __shared__ ushort As[2][4096];
    __shared__ ushort Bs[2][2048];
    __shared__ float ca[K], cd[K];
    __shared__ float red[2][64];
    const int t = threadIdx.x;
    const int lane = t & 63;
    const int w = t >> 6;
    const int m0 = blockIdx.y * 128;
    const int n0 = blockIdx.x * 64;
    const int la = lane & 15;
    const int lk = (lane >> 4) * 8;
    const int lks = lk ^ ((la & 3) << 3);
    const int srow = t >> 2;
    const int scol = ((t & 3) ^ (srow & 3)) * 8;
    const float invn = 1.f / (float)ROWS;

    for (int c = t; c < K; c += 256) {
        float m = psum[c] * invn;
        float var = psumsq[c] * invn - m * m;
        float a = pg[c] * rsqrtf(var + EPSV);
        ca[c] = a;
        cd[c] = pbt[c] - m * a;
    }
    if (t < 64) { red[0][t] = 0.f; red[1][t] = 0.f; }

    auto STAGE = [&](int buf, int k0) {
        GLOAD_LDS16(Araw + (size_t)(m0 + srow) * K + k0 + scol, &As[buf][t * 8]);
        GLOAD_LDS16(Araw + (size_t)(m0 + 64 + srow) * K + k0 + scol, &As[buf][2048 + t * 8]);
        GLOAD_LDS16(W + (size_t)(n0 + srow) * K + k0 + scol, &Bs[buf][t * 8]);
    };

    f32x4 acc[2][4];
#pragma unroll
    for (int fm = 0; fm < 2; ++fm)
#pragma unroll
        for (int fn = 0; fn < 4; ++fn) acc[fm][fn] = (f32x4){0.f, 0.f, 0.f, 0.f};

    STAGE(0, 0);
    __syncthreads();           // covers ca/cd + staged data
    int cur = 0;
    for (int ks = 0; ks < KS; ++ks) {
        const int k0 = ks * 32;
        if (ks + 1 < KS) STAGE(cur ^ 1, (ks + 1) * 32);
        s16x8 b0 = *reinterpret_cast<const s16x8*>(&Bs[cur][(0 + la) * 32 + lks]);
        s16x8 b1 = *reinterpret_cast<const s16x8*>(&Bs[cur][(16 + la) * 32 + lks]);
        s16x8 b2 = *reinterpret_cast<const s16x8*>(&Bs[cur][(32 + la) * 32 + lks]);
        s16x8 b3 = *reinterpret_cast<const s16x8*>(&Bs[cur][(48 + la) * 32 + lks]);
        // BN coefs for this k-slice (broadcast reads within 16-lane groups)
        float4 ka0 = *reinterpret_cast<const float4*>(&ca[k0 + lk]);
        float4 ka1 = *reinterpret_cast<const float4*>(&ca[k0 + lk + 4]);
        float4 kd0 = *reinterpret_cast<const float4*>(&cd[k0 + lk]);
        float4 kd1 = *reinterpret_cast<const float4*>(&cd[k0 + lk + 4]);
        float kaf[8] = {ka0.x, ka0.y, ka0.z, ka0.w, ka1.x, ka1.y, ka1.z, ka1.w};
        float kdf[8] = {kd0.x, kd0.y, kd0.z, kd0.w, kd1.x, kd1.y, kd1.z, kd1.w};
#pragma unroll
        for (int fm = 0; fm < 2; ++fm) {
            union { s16x8 v; ushort us[8]; } araw;
            araw.v = *reinterpret_cast<const s16x8*>(&As[cur][(w * 32 + fm * 16 + la) * 32 + lks]);
            float y[8];
#pragma unroll
            for (int e = 0; e < 8; ++e) {
                float f = bf2f(araw.us[e]);
                float z = fmaf(kaf[e], f, kdf[e]);
                y[e] = fmaxf(z, 0.f) + SLOPE * fminf(z, 0.f);
            }
            union { s16x8 v; unsigned u[4]; } af;
#pragma unroll
            for (int p = 0; p < 4; ++p) af.u[p] = cvt_pk_bf16(y[2 * p], y[2 * p + 1]);
            acc[fm][0] = __builtin_amdgcn_mfma_f32_16x16x32_bf16(af.v, b0, acc[fm][0], 0, 0, 0);
            acc[fm][1] = __builtin_amdgcn_mfma_f32_16x16x32_bf16(af.v, b1, acc[fm][1], 0, 0, 0);
            acc[fm][2] = __builtin_amdgcn_mfma_f32_16x16x32_bf16(af.v, b2, acc[fm][2], 0, 0, 0);
            acc[fm][3] = __builtin_amdgcn_mfma_f32_16x16x32_bf16(af.v, b3, acc[fm][3], 0, 0, 0);
        }
        __syncthreads();
        cur ^= 1;
    }

    float bv[4], s[4] = {}, q[4] = {};
#pragma unroll
    for (int fn = 0; fn < 4; ++fn) bv[fn] = bias[n0 + fn * 16 + la];
#pragma unroll
    for (int fm = 0; fm < 2; ++fm)
#pragma unroll
        for (int fn = 0; fn < 4; ++fn)
#pragma unroll
            for (int r = 0; r < 4; ++r) {
                int row = m0 + w * 32 + fm * 16 + (lane >> 4) * 4 + r;
                float v = acc[fm][fn][r] + bv[fn];
                Cb[(size_t)row * NC + n0 + fn * 16 + la] = f2bf(v);
                s[fn] += v; q[fn] += v * v;
            }
#pragma unroll
    for (int fn = 0; fn < 4; ++fn) {
        s[fn] += __shfl_xor(s[fn], 16); s[fn] += __shfl_xor(s[fn], 32);
        q[fn] += __shfl_xor(q[fn], 16); q[fn] += __shfl_xor(q[fn], 32);
    }
    if (lane < 16) {
#pragma unroll
        for (int fn = 0; fn < 4; ++fn) {
            atomicAdd(&red[0][fn * 16 + lane], s[fn]);
            atomicAdd(&red[1][fn * 16 + lane], q[fn]);
        }
    }
    __syncthreads();
    if (t < 64) {
        atomicAdd(&sums[n0 + t], red[0][t]);
        atomicAdd(&sumsq[n0 + t], red[1][t]);
    }
}

// ---------------------------------------------------------------------------
// Dispatch 4: gemm3. A = bf16 RAW Y2 (16x32 tile staged by wave 0),
// BN2+leaky in-register post-ds_read; C fp32 + stats.
// ---------------------------------------------------------------------------
__global__ __launch_bounds__(256) void k_gemm3_bn(const ushort* __restrict__ Araw,
                                                  const ushort* __restrict__ W,
                                                  const float* __restrict__ bias,
                                                  const float* __restrict__ psum,
                                                  const float* __restrict__ psumsq,
                                                  const float* __restrict__ pg,
                                                  const float* __restrict__ pbt,
                                                  float* __restrict__ C,
                                                  float* __restrict__ sums,
                                                  float* __restrict__ sumsq) {
    constexpr int K = 512, KS = 16;
    __shared__ ushort As[2][512];
    __shared__ ushort Bs[2][2048];
    __shared__ float ca[K], cd[K];
    const int t = threadIdx.x;
    const int lane = t & 63;
    const int w = t >> 6;
    const int m0 = blockIdx.x * 16;
    const int la = lane & 15;
    const int lk = (lane >> 4) * 8;
    const int lks = lk ^ ((la & 3) << 3);
    const int srow = t >> 2;
    const int scol = ((t & 3) ^ (srow & 3)) * 8;
    const int srow3 = lane >> 2;
    const int scol3 = ((lane & 3) ^ (srow3 & 3)) * 8;
    const float invn = 1.f / (float)ROWS;

    for (int c = t; c < K; c += 256) {
        float m = psum[c] * invn;
        float var = psumsq[c] * invn - m * m;
        float a = pg[c] * rsqrtf(var + EPSV);
        ca[c] = a;
        cd[c] = pbt[c] - m * a;
    }

    auto STAGE = [&](int buf, int k0) {
        if (w == 0)
            GLOAD_LDS16(Araw + (size_t)(m0 + srow3) * K + k0 + scol3, &As[buf][lane * 8]);
        GLOAD_LDS16(W + (size_t)srow * K + k0 + scol, &Bs[buf][t * 8]);
    };

    f32x4 acc = {0.f, 0.f, 0.f, 0.f};
    STAGE(0, 0);
    __syncthreads();
    int cur = 0;
    for (int ks = 0; ks < KS; ++ks) {
        const int k0 = ks * 32;
        if (ks + 1 < KS) STAGE(cur ^ 1, (ks + 1) * 32);
        float4 ka0 = *reinterpret_cast<const float4*>(&ca[k0 + lk]);
        float4 ka1 = *reinterpret_cast<const float4*>(&ca[k0 + lk + 4]);
        float4 kd0 = *reinterpret_cast<const float4*>(&cd[k0 + lk]);
        float4 kd1 = *reinterpret_cast<const float4*>(&cd[k0 + lk + 4]);
        float kaf[8] = {ka0.x, ka0.y, ka0.z, ka0.w, ka1.x, ka1.y, ka1.z, ka1.w};
        float kdf[8] = {kd0.x, kd0.y, kd0.z, kd0.w, kd1.x, kd1.y, kd1.z, kd1.w};
        union { s16x8 v; ushort us[8]; } araw;
        araw.v = *reinterpret_cast<const s16x8*>(&As[cur][la * 32 + lks]);
        float y[8];
#pragma unroll
        for (int e = 0; e < 8; ++e) {
            float f = bf2f(araw.us[e]);
            float z = fmaf(kaf[e], f, kdf[e]);
            y[e] = fmaxf(z, 0.f) + SLOPE * fminf(z, 0.f);
        }
        union { s16x8 v; unsigned u[4]; } af;
#pragma unroll
        for (int p = 0; p < 4; ++p) af.u[p] = cvt_pk_bf16(y[2 * p], y[2 * p + 1]);
        s16x8 bb = *reinterpret_cast<const s16x8*>(&Bs[cur][(w * 16 + la) * 32 + lks]);
        acc = __builtin_amdgcn_mfma_f32_16x16x32_bf16(af.v, bb, acc, 0, 0, 0);
        __syncthreads();
        cur ^= 1;
    }

    float bv = bias[w * 16 + la];
    float s = 0.f, q = 0.f;
#pragma unroll
    for (int r = 0; r < 4; ++r) {
        int row = m0 + (lane >> 4) * 4 + r;
        float v = acc[r] + bv;
        C[(size_t)row * NO + w * 16 + la] = v;
        s += v; q += v * v;
    }
    s += __shfl_xor(s, 16); s += __shfl_xor(s, 32);
    q += __shfl_xor(q, 16); q += __shfl_xor(q, 32);
    if (lane < 16) {
        atomicAdd(&sums[w * 16 + la], s);
        atomicAdd(&sumsq[w * 16 + la], q);
    }
}

// ---------------------------------------------------------------------------
// Dispatch 5: final BN -> out.
// ---------------------------------------------------------------------------
__global__ __launch_bounds__(256) void k_bn3(const float* __restrict__ Yin,
                                             float* __restrict__ Yout,
                                             const float* __restrict__ sums,
                                             const float* __restrict__ sumsq,
                                             const float* __restrict__ g,
                                             const float* __restrict__ bt) {
    const float invn = 1.f / (float)ROWS;
    int e = blockIdx.x * 256 + threadIdx.x;
    int c0 = (e * 4) & (NO - 1);
    float4 v = reinterpret_cast<const float4*>(Yin)[e];
    float vv[4] = {v.x, v.y, v.z, v.w};
    float oo[4];
#pragma unroll
    for (int j = 0; j < 4; ++j) {
        int c = c0 + j;
        float m = sums[c] * invn;
        float var = sumsq[c] * invn - m * m;
        float rs = rsqrtf(var + EPSV);
        oo[j] = (vv[j] - m) * rs * g[c] + bt[c];
    }
    reinterpret_cast<float4*>(Yout)[e] = make_float4(oo[0], oo[1], oo[2], oo[3]);
}

extern "C" void kernel_launch(void* const* d_in, const int* in_sizes, int n_in,
                              void* d_out, int out_size, void* d_ws, size_t ws_size,
                              hipStream_t stream) {
    const float* x   = (const float*)d_in[0];
    const float* Q   = (const float*)d_in[1];
    const float* W1  = (const float*)d_in[2];
    const float* b1  = (const float*)d_in[3];
    const float* g1  = (const float*)d_in[4];
    const float* bt1 = (const float*)d_in[5];
    const float* W2  = (const float*)d_in[6];
    const float* b2  = (const float*)d_in[7];
    const float* g2  = (const float*)d_in[8];
    const float* bt2 = (const float*)d_in[9];
    const float* W3  = (const float*)d_in[10];
    const float* b3  = (const float*)d_in[11];
    const float* g3  = (const float*)d_in[12];
    const float* bt3 = (const float*)d_in[13];
    float* out = (float*)d_out;

    char* wsb = (char*)d_ws;
    ushort* Vb   = (ushort*)wsb;                     // [0,4M)   bf16 8192x256
    ushort* Y1rb = (ushort*)(wsb + (4u << 20));      // [4,12M)  bf16 raw 8192x512
    ushort* Y2rb = (ushort*)(wsb + (12u << 20));     // [12,20M) bf16 raw 8192x512
    float*  Yr3  = (float*)(wsb + (20u << 20));      // [20,22M) fp32 8192x64
    ushort* W1b  = (ushort*)(wsb + (24u << 20));
    ushort* W2b  = W1b + 512 * 256;
    ushort* W3b  = W2b + 512 * 512;
    float*  st   = (float*)(W3b + 64 * 512);
    float* s1 = st;        float* q1 = s1 + 512;
    float* s2 = q1 + 512;  float* q2 = s2 + 512;
    float* s3 = q2 + 512;  float* q3 = s3 + 64;

    k_getv_wconv<<<576, 256, 0, stream>>>(x, Q, Vb, W1, W2, W3, W1b, W2b, W3b, st);

    k_gemm1<<<dim3(8, 64), 256, 0, stream>>>(Vb, W1b, b1, Y1rb, s1, q1);

    k_gemm_bn<512, 512><<<dim3(8, 64), 256, 0, stream>>>(
        Y1rb, W2b, b2, s1, q1, g1, bt1, Y2rb, s2, q2);

    k_gemm3_bn<<<512, 256, 0, stream>>>(
        Y2rb, W3b, b3, s2, q2, g2, bt2, Yr3, s3, q3);

    k_bn3<<<512, 256, 0, stream>>>(Yr3, out, s3, q3, g3, bt3);
}